// Round 3
// baseline (1003.419 us; speedup 1.0000x reference)
//
#include <hip/hip_runtime.h>
#include <stdint.h>

#define B_TOK 8192
#define DDIM 1024
#define HDIM 4096
#define NEXP 8
#define MAXTILE 72  // max sum ceil(cnt_e/256) = 16384/256 + 8

typedef __bf16 bf16x8 __attribute__((ext_vector_type(8)));
typedef float f32x4 __attribute__((ext_vector_type(4)));

__device__ __forceinline__ unsigned short f2bf(float f) {
  unsigned int u = __float_as_uint(f);
  u += 0x7fffu + ((u >> 16) & 1u);  // round-to-nearest-even
  return (unsigned short)(u >> 16);
}
__device__ __forceinline__ float bfhi(unsigned int u) {  // high bf16 of packed u32
  return __uint_as_float(u & 0xffff0000u);
}
__device__ __forceinline__ float bflo(unsigned int u) {  // low bf16
  return __uint_as_float(u << 16);
}

__device__ __forceinline__ void gld16(const void* g, void* l) {
  __builtin_amdgcn_global_load_lds(
      (const __attribute__((address_space(1))) void*)g,
      (__attribute__((address_space(3))) void*)l, 16, 0, 0);
}

// tanh-form GELU; max abs err ~3e-4 (well under bf16 rounding of h)
__device__ __forceinline__ float gelu_f(float v) {
  float u = v * (0.7978845608f + 0.0356774081f * v * v);
  float ex = __expf(2.f * u);
  float th = 1.f - 2.f * __builtin_amdgcn_rcpf(ex + 1.f);  // tanh(u), saturates correctly
  return 0.5f * v * (1.f + th);
}

// ---------------- gating: logits -> top2 -> renorm weights (+ fused x->bf16 cast) ----------------
__global__ __launch_bounds__(256) void gating_kernel(
    const float* __restrict__ x, const float* __restrict__ Wg,
    const float* __restrict__ bg, int* __restrict__ t2e,
    float* __restrict__ t2w, int* __restrict__ cnt,
    unsigned short* __restrict__ xb) {
  __shared__ float sWg[NEXP * DDIM];  // [e][d]
  int tid = threadIdx.x;
  for (int i = tid; i < NEXP * DDIM; i += 256) {
    int d = i >> 3, e = i & 7;
    sWg[e * DDIM + d] = Wg[i];
  }
  __syncthreads();
  int lane = tid & 63, wave = tid >> 6;
  for (int t = 0; t < 8; ++t) {
    int b = blockIdx.x * 32 + wave * 8 + t;
    float acc[NEXP];
#pragma unroll
    for (int e = 0; e < NEXP; ++e) acc[e] = 0.f;
    const float* xr = x + (size_t)b * DDIM;
    unsigned short* xw = xb + (size_t)b * DDIM;
#pragma unroll
    for (int j = 0; j < 4; ++j) {
      int d0 = j * 256 + lane * 4;
      float4 xv = *(const float4*)(xr + d0);
      ushort4 o;
      o.x = f2bf(xv.x); o.y = f2bf(xv.y); o.z = f2bf(xv.z); o.w = f2bf(xv.w);
      *(ushort4*)(xw + d0) = o;
#pragma unroll
      for (int e = 0; e < NEXP; ++e) {
        float4 wv = *(const float4*)(sWg + e * DDIM + d0);
        acc[e] += xv.x * wv.x + xv.y * wv.y + xv.z * wv.z + xv.w * wv.w;
      }
    }
#pragma unroll
    for (int off = 32; off > 0; off >>= 1) {
#pragma unroll
      for (int e = 0; e < NEXP; ++e) acc[e] += __shfl_xor(acc[e], off);
    }
    if (lane == 0) {
      float l0[NEXP];
#pragma unroll
      for (int e = 0; e < NEXP; ++e) l0[e] = acc[e] + bg[e];
      int i1 = 0;
      float v1 = l0[0];
#pragma unroll
      for (int e = 1; e < NEXP; ++e)
        if (l0[e] > v1) { v1 = l0[e]; i1 = e; }
      int i2 = (i1 == 0) ? 1 : 0;
      float v2 = l0[i2];
#pragma unroll
      for (int e = 0; e < NEXP; ++e)
        if (e != i1 && l0[e] > v2) { v2 = l0[e]; i2 = e; }
      float w1 = 1.f / (1.f + expf(v2 - v1));  // renorm top-2 softmax
      float w2 = 1.f - w1;
      t2e[b * 2] = i1;
      t2e[b * 2 + 1] = i2;
      t2w[b * 2] = w1;
      t2w[b * 2 + 1] = w2;
      atomicAdd(&cnt[i1], 1);
      atomicAdd(&cnt[i2], 1);
    }
  }
}

// serial: offsets + flat (expert, m-tile) work queue (BM=256 granularity)
// also per-expert gemm1 item counts (for the ybuf/w1t alias guard)
__global__ void prefix_kernel(const int* __restrict__ cnt, int* __restrict__ offs,
                              int* __restrict__ tileE, int* __restrict__ tileM,
                              int* __restrict__ ntile, int* __restrict__ g1cnt) {
  int s = 0, t = 0;
  offs[0] = 0;
  for (int e = 0; e < NEXP; ++e) {
    int c = cnt[e];
    int t0 = t;
    for (int m = 0; m < c; m += 256) { tileE[t] = e; tileM[t] = m; ++t; }
    g1cnt[e] = 16 * (t - t0);
    s += c;
    offs[e + 1] = s;
  }
  *ntile = t;
}

// LDS-aggregated scatter: one global atomic per (block, expert) instead of per token slot
__global__ __launch_bounds__(256) void scatter_kernel(
    const int* __restrict__ t2e, const int* __restrict__ offs,
    int* __restrict__ cursor, int* __restrict__ tok, int* __restrict__ rowpos) {
  __shared__ int lcnt[NEXP], lbase[NEXP];
  int tid = threadIdx.x;
  if (tid < NEXP) lcnt[tid] = 0;
  __syncthreads();
  int b = blockIdx.x * 256 + tid;
  int e0 = t2e[b * 2], e1 = t2e[b * 2 + 1];
  int i0 = atomicAdd(&lcnt[e0], 1);
  int i1 = atomicAdd(&lcnt[e1], 1);
  __syncthreads();
  if (tid < NEXP) lbase[tid] = atomicAdd(&cursor[tid], lcnt[tid]);
  __syncthreads();
  int p0 = offs[e0] + lbase[e0] + i0;
  int p1 = offs[e1] + lbase[e1] + i1;
  tok[p0] = b;
  tok[p1] = b;
  rowpos[b * 2] = p0;
  rowpos[b * 2 + 1] = p1;
}

// src [R][C] f32 (expert z) -> dst [C][R] bf16; 64x64 tiles, vectorized both sides
__global__ __launch_bounds__(256) void transpose_cvt_kernel(
    const float* __restrict__ src, unsigned short* __restrict__ dst, int R, int C) {
  __shared__ unsigned short T[64][72];
  size_t eo = (size_t)blockIdx.z * (size_t)R * C;
  int c0 = blockIdx.x * 64, r0 = blockIdx.y * 64;
  int tid = threadIdx.x;
#pragma unroll
  for (int p = 0; p < 4; ++p) {
    int idx = p * 256 + tid;
    int r = idx >> 4, c4 = (idx & 15) * 4;
    float4 v = *(const float4*)(src + eo + (size_t)(r0 + r) * C + c0 + c4);
    T[r][c4] = f2bf(v.x);
    T[r][c4 + 1] = f2bf(v.y);
    T[r][c4 + 2] = f2bf(v.z);
    T[r][c4 + 3] = f2bf(v.w);
  }
  __syncthreads();
#pragma unroll
  for (int p = 0; p < 2; ++p) {
    int idx = p * 256 + tid;
    int c = idx >> 3, s8 = (idx & 7) * 8;
    ushort4 a, b;
    a.x = T[s8][c];     a.y = T[s8 + 1][c]; a.z = T[s8 + 2][c]; a.w = T[s8 + 3][c];
    b.x = T[s8 + 4][c]; b.y = T[s8 + 5][c]; b.z = T[s8 + 6][c]; b.w = T[s8 + 7][c];
    unsigned short* dp = dst + eo + (size_t)(c0 + c) * R + r0 + s8;
    *(ushort4*)dp = a;
    *(ushort4*)(dp + 4) = b;
  }
}

// ---------------- grouped GEMM tile, 256x256, BK=64, reg-double-buffered 4-phase pipeline ----------------
// (schedule identical to R2 kernel; see comments there)
#define BAR() __builtin_amdgcn_s_barrier()
#define SB() __builtin_amdgcn_sched_barrier(0)
#define LG0() asm volatile("s_waitcnt lgkmcnt(0)" ::: "memory")
#define VMW(n) asm volatile("s_waitcnt vmcnt(" #n ")" ::: "memory")
#define RGN(t, mat, ks) (&LDS[(t) & 1][mat][ks][0][0])
#define STAGE(mat, P0p, P1p, t, ks)                                 \
  do {                                                              \
    unsigned short* _d = RGN(t, mat, ks) + wave * 512;              \
    gld16((P0p) + (size_t)(t) * 64 + (ks) * 32, _d);                \
    gld16((P1p) + (size_t)(t) * 64 + (ks) * 32, _d + 4096);         \
  } while (0)
#define RDA_TO(dst, t, ks)                                          \
  do {                                                              \
    const unsigned short* _p = RGN(t, 0, ks);                       \
    _Pragma("unroll") for (int n = 0; n < 4; ++n)                   \
        dst[n] = *(const bf16x8*)(_p + aoff[n]);                    \
  } while (0)
#define RDB_TO(dst, t, ks, h)                                       \
  do {                                                              \
    const unsigned short* _p = RGN(t, 1, ks);                       \
    _Pragma("unroll") for (int m = 0; m < 4; ++m)                   \
        dst[m] = *(const bf16x8*)(_p + boff2[h][m]);                \
  } while (0)
#define MMQ2(Av, Bv, h)                                             \
  do {                                                              \
    __builtin_amdgcn_s_setprio(1);                                  \
    _Pragma("unroll") for (int i = 0; i < 4; ++i)                   \
        _Pragma("unroll") for (int j = 0; j < 4; ++j)               \
            acc[i][(h)*4 + j] = __builtin_amdgcn_mfma_f32_16x16x32_bf16( \
                Av[i], Bv[j], acc[i][(h)*4 + j], 0, 0, 0);          \
    __builtin_amdgcn_s_setprio(0);                                  \
  } while (0)

typedef unsigned short LdsT[2][2][2][256][32];

template <int NT, bool GELU, bool GATHER>
__device__ __forceinline__ void run_tile(
    const unsigned short* __restrict__ Bsrc, const unsigned short* __restrict__ Wt,
    const float* __restrict__ bias, const int* __restrict__ tok,
    unsigned short* __restrict__ obuf, int ND,
    int e, int m0, int r0, int rows, int n0, LdsT& LDS) {
  constexpr int KD = NT * 64;
  static_assert(NT >= 3, "pipeline needs >=3 K-tiles");
  int tid = threadIdx.x, lane = tid & 63, wave = tid >> 6;
  int wn = wave & 3, wm = wave >> 2;
  int nbase = wn * 64, mbase = wm * 128;
  int fr = lane & 15, quad = lane >> 4;

  // staging source mapping: thread covers segs tid and 512+tid (linear LDS dest);
  // global seg pre-swizzled so that read-side XOR recovers it.
  int rs = tid >> 2;
  int ss = (tid & 3) ^ ((rs >> 1) & 3);  // same for both issues (row+128 keeps (r>>1)&3)
  const unsigned short* pA0 = Wt + ((size_t)e * ND + n0 + rs) * KD + ss * 8;
  const unsigned short* pA1 = pA0 + (size_t)128 * KD;
  int mr0 = min(m0 + rs, rows - 1), mr1 = min(m0 + 128 + rs, rows - 1);
  size_t br0, br1;
  if constexpr (GATHER) {
    br0 = (size_t)tok[r0 + mr0];
    br1 = (size_t)tok[r0 + mr1];
  } else {
    br0 = (size_t)(r0 + mr0);
    br1 = (size_t)(r0 + mr1);
  }
  const unsigned short* pB0 = Bsrc + br0 * KD + ss * 8;
  const unsigned short* pB1 = Bsrc + br1 * KD + ss * 8;

  // fragment read offsets (ushort units), swizzled
  int aoff[4], boff2[2][4];
#pragma unroll
  for (int n = 0; n < 4; ++n) {
    int rA = nbase + n * 16 + fr;
    aoff[n] = rA * 32 + (quad ^ ((rA >> 1) & 3)) * 8;
  }
#pragma unroll
  for (int h = 0; h < 2; ++h)
#pragma unroll
    for (int m = 0; m < 4; ++m) {
      int rB = mbase + h * 64 + m * 16 + fr;
      boff2[h][m] = rB * 32 + (quad ^ ((rB >> 1) & 3)) * 8;
    }

  f32x4 acc[4][8];
#pragma unroll
  for (int i = 0; i < 4; ++i)
#pragma unroll
    for (int j = 0; j < 8; ++j) acc[i][j] = (f32x4){0.f, 0.f, 0.f, 0.f};
  bf16x8 aE[4], aO[4], bE[4], bO[4];

  // prologue: tile0 complete + tile1 {A0,B0,A1}; B1(1) staged at (0,P0)
  STAGE(0, pA0, pA1, 0, 0);
  STAGE(1, pB0, pB1, 0, 0);
  STAGE(0, pA0, pA1, 0, 1);
  STAGE(1, pB0, pB1, 0, 1);
  STAGE(0, pA0, pA1, 1, 0);
  STAGE(1, pB0, pB1, 1, 0);
  STAGE(0, pA0, pA1, 1, 1);
  VMW(10);  // A0(0),B0(0) landed
  BAR();
  RDA_TO(aE, 0, 0);
  RDB_TO(bE, 0, 0, 0);
  LG0();
  SB();

  for (int t = 0; t < NT - 2; ++t) {
    // P0: compute (ks0,h0) | read B0(t)h1 | stage B1(t+1)
    RDB_TO(bO, t, 0, 1);
    STAGE(1, pB0, pB1, t + 1, 1);
    SB();
    MMQ2(aE, bE, 0);
    SB();
    VMW(8); LG0(); SB();
    BAR();
    // P1: compute (ks0,h1) | read A1(t), B1(t)h0 | stage A0(t+2)
    RDA_TO(aO, t, 1);
    RDB_TO(bE, t, 1, 0);
    STAGE(0, pA0, pA1, t + 2, 0);
    SB();
    MMQ2(aE, bO, 1);
    SB();
    LG0(); SB();
    BAR();
    // P2: compute (ks1,h0) | read B1(t)h1 | stage B0(t+2)
    RDB_TO(bO, t, 1, 1);
    STAGE(1, pB0, pB1, t + 2, 0);
    SB();
    MMQ2(aO, bE, 0);
    SB();
    VMW(8); LG0(); SB();
    BAR();
    // P3: compute (ks1,h1) | read A0(t+1), B0(t+1)h0 | stage A1(t+2)
    RDA_TO(aE, t + 1, 0);
    RDB_TO(bE, t + 1, 0, 0);
    STAGE(0, pA0, pA1, t + 2, 1);
    SB();
    MMQ2(aO, bO, 1);
    SB();
    LG0(); SB();
    BAR();
  }
  {  // tile NT-2: only B1(NT-1) left to stage
    int t = NT - 2;
    RDB_TO(bO, t, 0, 1);
    STAGE(1, pB0, pB1, t + 1, 1);
    SB(); MMQ2(aE, bE, 0); SB();
    VMW(8); LG0(); SB();
    BAR();
    RDA_TO(aO, t, 1);
    RDB_TO(bE, t, 1, 0);
    SB(); MMQ2(aE, bO, 1); SB();
    LG0(); SB();
    BAR();
    RDB_TO(bO, t, 1, 1);
    SB(); MMQ2(aO, bE, 0); SB();
    VMW(4); LG0(); SB();  // A0(NT-1),B0(NT-1) landed
    BAR();
    RDA_TO(aE, t + 1, 0);
    RDB_TO(bE, t + 1, 0, 0);
    SB(); MMQ2(aO, bO, 1); SB();
    LG0(); SB();
    BAR();
  }
  {  // tile NT-1: compute only
    int t = NT - 1;
    RDB_TO(bO, t, 0, 1);
    SB(); MMQ2(aE, bE, 0); SB();
    VMW(0); LG0(); SB();  // A1(NT-1),B1(NT-1) landed
    BAR();
    RDA_TO(aO, t, 1);
    RDB_TO(bE, t, 1, 0);
    SB(); MMQ2(aE, bO, 1); SB();
    LG0(); SB();
    BAR();
    RDB_TO(bO, t, 1, 1);
    SB(); MMQ2(aO, bE, 0); SB();
    LG0(); SB();
    BAR();
    SB(); MMQ2(aO, bO, 1); SB();
  }

  // epilogue: acc[i][J] -> out row m0+mbase+(J>>2)*64+(J&3)*16+fr,
  //           cols n0+nbase+i*16+quad*4+[0..3]
  const float* be = bias + (size_t)e * ND + n0 + nbase;
  float4 bv[4];
#pragma unroll
  for (int i = 0; i < 4; ++i) bv[i] = *(const float4*)(be + i * 16 + quad * 4);
#pragma unroll
  for (int j = 0; j < 8; ++j) {
    int grow = m0 + mbase + (j >> 2) * 64 + (j & 3) * 16 + fr;
    if (grow < rows) {
      unsigned short* yp = obuf + (size_t)(r0 + grow) * ND + n0 + nbase;
#pragma unroll
      for (int i = 0; i < 4; ++i) {
        float v0 = acc[i][j][0] + bv[i].x;
        float v1 = acc[i][j][1] + bv[i].y;
        float v2 = acc[i][j][2] + bv[i].z;
        float v3 = acc[i][j][3] + bv[i].w;
        if constexpr (GELU) {
          v0 = gelu_f(v0); v1 = gelu_f(v1); v2 = gelu_f(v2); v3 = gelu_f(v3);
        }
        ushort4 o;
        o.x = f2bf(v0); o.y = f2bf(v1); o.z = f2bf(v2); o.w = f2bf(v3);
        *(ushort4*)(yp + i * 16 + quad * 4) = o;
      }
    }
  }
}

// ---------------- fused persistent MoE: gemm1 items then gemm2 items off one queue ----------------
// Queue order guarantees deadlock freedom: any spin waits only on earlier-dispensed items.
// Producer publish: __syncthreads (drains stores to L2) -> agent-release add (wbL2 -> L3).
// Consumer: relaxed agent spin + one acquire load (invL2) before reading hbuf.
// ybuf aliases w1t: gemm2 writes additionally guarded by done1E[expert region row>>12].
__global__ __launch_bounds__(512, 2) void moe_fused(
    const unsigned short* __restrict__ xb, const unsigned short* __restrict__ w1t,
    const float* __restrict__ b1, const unsigned short* __restrict__ w2t,
    const float* __restrict__ b2, const int* __restrict__ offs,
    const int* __restrict__ tileE, const int* __restrict__ tileM,
    const int* __restrict__ ntile, const int* __restrict__ tok,
    const int* __restrict__ g1cnt, unsigned short* __restrict__ hbuf,
    unsigned short* __restrict__ ybuf, int* __restrict__ qhead,
    int* __restrict__ done, int* __restrict__ done1E) {
  __shared__ __attribute__((aligned(16))) unsigned short LDS[2][2][2][256][32];  // 128 KiB
  __shared__ int s_it;
  int nt = *ntile;
  int n1 = nt * 16;
  int nall = n1 + nt * 4;
  int tid = threadIdx.x;
  for (;;) {
    __syncthreads();  // protect s_it rewrite + LDS reuse vs previous item
    if (tid == 0) s_it = atomicAdd(qhead, 1);
    __syncthreads();
    int it = s_it;
    if (it >= nall) return;
    if (it < n1) {
      int ty = it >> 4, nx = it & 15;
      int e = tileE[ty], m0 = tileM[ty];
      int r0 = offs[e], rows = offs[e + 1] - r0;
      run_tile<DDIM / 64, true, true>(xb, w1t, b1, tok, hbuf, HDIM, e, m0, r0, rows,
                                      nx * 256, LDS);
      __syncthreads();  // all hbuf stores drained (vmcnt0) before publish
      if (tid == 0) {
        __hip_atomic_fetch_add(&done[ty], 1, __ATOMIC_RELEASE, __HIP_MEMORY_SCOPE_AGENT);
        __hip_atomic_fetch_add(&done1E[e], 1, __ATOMIC_RELEASE, __HIP_MEMORY_SCOPE_AGENT);
      }
    } else {
      int q = it - n1;
      int ty = q >> 2, nx = q & 3;
      int e = tileE[ty], m0 = tileM[ty];
      int r0 = offs[e], rows = offs[e + 1] - r0;
      if (tid == 0) {
        while (__hip_atomic_load(&done[ty], __ATOMIC_RELAXED, __HIP_MEMORY_SCOPE_AGENT) < 16)
          __builtin_amdgcn_s_sleep(2);
        // ybuf aliases w1t[0:32M): wait until overlapped expert regions fully read
        int eA = (r0 + m0) >> 12;
        int eB = (r0 + m0 + 255) >> 12;
        while (__hip_atomic_load(&done1E[eA], __ATOMIC_RELAXED, __HIP_MEMORY_SCOPE_AGENT) <
               g1cnt[eA])
          __builtin_amdgcn_s_sleep(2);
        while (__hip_atomic_load(&done1E[eB], __ATOMIC_RELAXED, __HIP_MEMORY_SCOPE_AGENT) <
               g1cnt[eB])
          __builtin_amdgcn_s_sleep(2);
        (void)__hip_atomic_load(&done[ty], __ATOMIC_ACQUIRE, __HIP_MEMORY_SCOPE_AGENT);
      }
      __syncthreads();
      run_tile<HDIM / 64, false, false>(hbuf, w2t, b2, tok, ybuf, DDIM, e, m0, r0, rows,
                                        nx * 256, LDS);
    }
  }
}

// ---------------- combine: out[b] = w0*y[row0] + w1*y[row1] ----------------
__global__ __launch_bounds__(256) void combine_kernel(
    const unsigned short* __restrict__ ybuf, const int* __restrict__ rowpos,
    const float* __restrict__ t2w, float* __restrict__ out) {
  int idx = blockIdx.x * 256 + threadIdx.x;  // B*D/8 threads
  int b = idx >> 7;
  int c8 = (idx & 127) * 8;
  int p0 = rowpos[b * 2], p1 = rowpos[b * 2 + 1];
  float w0 = t2w[b * 2], w1 = t2w[b * 2 + 1];
  uint4 ya = *(const uint4*)(ybuf + (size_t)p0 * DDIM + c8);
  uint4 yb = *(const uint4*)(ybuf + (size_t)p1 * DDIM + c8);
  float4 o0, o1;
  o0.x = w0 * bflo(ya.x) + w1 * bflo(yb.x);
  o0.y = w0 * bfhi(ya.x) + w1 * bfhi(yb.x);
  o0.z = w0 * bflo(ya.y) + w1 * bflo(yb.y);
  o0.w = w0 * bfhi(ya.y) + w1 * bfhi(yb.y);
  o1.x = w0 * bflo(ya.z) + w1 * bflo(yb.z);
  o1.y = w0 * bfhi(ya.z) + w1 * bfhi(yb.z);
  o1.z = w0 * bflo(ya.w) + w1 * bflo(yb.w);
  o1.w = w0 * bfhi(ya.w) + w1 * bfhi(yb.w);
  float* op = out + (size_t)b * DDIM + c8;
  *(float4*)op = o0;
  *(float4*)(op + 4) = o1;
}

extern "C" void kernel_launch(void* const* d_in, const int* in_sizes, int n_in,
                              void* d_out, int out_size, void* d_ws, size_t ws_size,
                              hipStream_t stream) {
  const float* x = (const float*)d_in[0];
  const float* Wg = (const float*)d_in[1];
  const float* bg = (const float*)d_in[2];
  const float* W1 = (const float*)d_in[3];
  const float* b1 = (const float*)d_in[4];
  const float* W2 = (const float*)d_in[5];
  const float* b2 = (const float*)d_in[6];
  float* out = (float*)d_out;

  char* ws = (char*)d_ws;
  int* cnt = (int*)(ws + 0);
  int* cursor = (int*)(ws + 64);
  int* offs = (int*)(ws + 128);
  int* ntile = (int*)(ws + 192);
  int* qhead = (int*)(ws + 196);
  int* done = (int*)(ws + 256);     // [256,544)
  int* done1E = (int*)(ws + 544);   // [544,576)
  int* g1cnt = (int*)(ws + 576);    // [576,608)
  int* tileE = (int*)(ws + 640);    // [640,928)
  int* tileM = (int*)(ws + 960);    // [960,1248)
  int* t2e = (int*)(ws + 2048);
  float* t2w = (float*)(ws + 67584);
  int* tok = (int*)(ws + 133120);
  int* rowpos = (int*)(ws + 198656);
  char* big = ws + 264192;
  unsigned short* xb = (unsigned short*)big;                              // 16 MiB
  unsigned short* w1t = (unsigned short*)(big + 16777216);                // 64 MiB
  unsigned short* ybuf = w1t;  // alias: guarded in-kernel by done1E
  unsigned short* w2t = (unsigned short*)(big + 16777216 + 67108864);     // 64 MiB
  unsigned short* hbuf = (unsigned short*)(big + 16777216 + 2 * 67108864);// 128 MiB

  (void)in_sizes; (void)n_in; (void)out_size; (void)ws_size;

  hipMemsetAsync(ws, 0, 1280, stream);

  transpose_cvt_kernel<<<dim3(HDIM / 64, DDIM / 64, NEXP), 256, 0, stream>>>(W1, w1t, DDIM, HDIM);
  transpose_cvt_kernel<<<dim3(DDIM / 64, HDIM / 64, NEXP), 256, 0, stream>>>(W2, w2t, HDIM, DDIM);
  gating_kernel<<<B_TOK / 32, 256, 0, stream>>>(x, Wg, bg, t2e, t2w, cnt, xb);
  prefix_kernel<<<1, 1, 0, stream>>>(cnt, offs, tileE, tileM, ntile, g1cnt);
  scatter_kernel<<<B_TOK / 256, 256, 0, stream>>>(t2e, offs, cursor, tok, rowpos);
  moe_fused<<<256, 512, 0, stream>>>(xb, w1t, b1, w2t, b2, offs, tileE, tileM, ntile,
                                     tok, g1cnt, hbuf, ybuf, qhead, done, done1E);
  combine_kernel<<<(B_TOK * DDIM) / (256 * 8), 256, 0, stream>>>(ybuf, rowpos, t2w, out);
}

// Round 4
// 901.007 us; speedup vs baseline: 1.1137x; 1.1137x over previous
//
#include <hip/hip_runtime.h>
#include <stdint.h>

#define B_TOK 8192
#define DDIM 1024
#define HDIM 4096
#define NEXP 8
#define MAXTILE 72  // max sum ceil(cnt_e/256) = 16384/256 + 8

typedef __bf16 bf16x8 __attribute__((ext_vector_type(8)));
typedef float f32x4 __attribute__((ext_vector_type(4)));
typedef unsigned short u16x8 __attribute__((ext_vector_type(8)));

__device__ __forceinline__ unsigned short f2bf(float f) {
  unsigned int u = __float_as_uint(f);
  u += 0x7fffu + ((u >> 16) & 1u);  // round-to-nearest-even
  return (unsigned short)(u >> 16);
}
__device__ __forceinline__ float bfhi(unsigned int u) {  // high bf16 of packed u32
  return __uint_as_float(u & 0xffff0000u);
}
__device__ __forceinline__ float bflo(unsigned int u) {  // low bf16
  return __uint_as_float(u << 16);
}

__device__ __forceinline__ void gld16(const void* g, void* l) {
  __builtin_amdgcn_global_load_lds(
      (const __attribute__((address_space(1))) void*)g,
      (__attribute__((address_space(3))) void*)l, 16, 0, 0);
}

// tanh-form GELU; max abs err ~3e-4 (well under bf16 rounding of h)
__device__ __forceinline__ float gelu_f(float v) {
  float u = v * (0.7978845608f + 0.0356774081f * v * v);
  float ex = __expf(2.f * u);
  float th = 1.f - 2.f * __builtin_amdgcn_rcpf(ex + 1.f);  // tanh(u), saturates correctly
  return 0.5f * v * (1.f + th);
}

// ---------------- gating: logits -> top2 -> renorm weights (+ fused x->bf16 cast) ----------------
__global__ __launch_bounds__(256) void gating_kernel(
    const float* __restrict__ x, const float* __restrict__ Wg,
    const float* __restrict__ bg, int* __restrict__ t2e,
    float* __restrict__ t2w, int* __restrict__ cnt,
    unsigned short* __restrict__ xb) {
  __shared__ float sWg[NEXP * DDIM];  // [e][d]
  int tid = threadIdx.x;
  for (int i = tid; i < NEXP * DDIM; i += 256) {
    int d = i >> 3, e = i & 7;
    sWg[e * DDIM + d] = Wg[i];
  }
  __syncthreads();
  int lane = tid & 63, wave = tid >> 6;
  for (int t = 0; t < 8; ++t) {
    int b = blockIdx.x * 32 + wave * 8 + t;
    float acc[NEXP];
#pragma unroll
    for (int e = 0; e < NEXP; ++e) acc[e] = 0.f;
    const float* xr = x + (size_t)b * DDIM;
    unsigned short* xw = xb + (size_t)b * DDIM;
#pragma unroll
    for (int j = 0; j < 4; ++j) {
      int d0 = j * 256 + lane * 4;
      float4 xv = *(const float4*)(xr + d0);
      ushort4 o;
      o.x = f2bf(xv.x); o.y = f2bf(xv.y); o.z = f2bf(xv.z); o.w = f2bf(xv.w);
      *(ushort4*)(xw + d0) = o;
#pragma unroll
      for (int e = 0; e < NEXP; ++e) {
        float4 wv = *(const float4*)(sWg + e * DDIM + d0);
        acc[e] += xv.x * wv.x + xv.y * wv.y + xv.z * wv.z + xv.w * wv.w;
      }
    }
#pragma unroll
    for (int off = 32; off > 0; off >>= 1) {
#pragma unroll
      for (int e = 0; e < NEXP; ++e) acc[e] += __shfl_xor(acc[e], off);
    }
    if (lane == 0) {
      float l0[NEXP];
#pragma unroll
      for (int e = 0; e < NEXP; ++e) l0[e] = acc[e] + bg[e];
      int i1 = 0;
      float v1 = l0[0];
#pragma unroll
      for (int e = 1; e < NEXP; ++e)
        if (l0[e] > v1) { v1 = l0[e]; i1 = e; }
      int i2 = (i1 == 0) ? 1 : 0;
      float v2 = l0[i2];
#pragma unroll
      for (int e = 0; e < NEXP; ++e)
        if (e != i1 && l0[e] > v2) { v2 = l0[e]; i2 = e; }
      float w1 = 1.f / (1.f + expf(v2 - v1));  // renorm top-2 softmax
      float w2 = 1.f - w1;
      t2e[b * 2] = i1;
      t2e[b * 2 + 1] = i2;
      t2w[b * 2] = w1;
      t2w[b * 2 + 1] = w2;
      atomicAdd(&cnt[i1], 1);
      atomicAdd(&cnt[i2], 1);
    }
  }
}

// serial: offsets + flat (expert, m-tile) work queue (BM=256 granularity)
__global__ void prefix_kernel(const int* __restrict__ cnt, int* __restrict__ offs,
                              int* __restrict__ tileE, int* __restrict__ tileM,
                              int* __restrict__ ntile) {
  int s = 0, t = 0;
  offs[0] = 0;
  for (int e = 0; e < NEXP; ++e) {
    int c = cnt[e];
    for (int m = 0; m < c; m += 256) { tileE[t] = e; tileM[t] = m; ++t; }
    s += c;
    offs[e + 1] = s;
  }
  *ntile = t;
}

// LDS-aggregated scatter: one global atomic per (block, expert) instead of per token slot
__global__ __launch_bounds__(256) void scatter_kernel(
    const int* __restrict__ t2e, const int* __restrict__ offs,
    int* __restrict__ cursor, int* __restrict__ tok, int* __restrict__ rowpos) {
  __shared__ int lcnt[NEXP], lbase[NEXP];
  int tid = threadIdx.x;
  if (tid < NEXP) lcnt[tid] = 0;
  __syncthreads();
  int b = blockIdx.x * 256 + tid;
  int e0 = t2e[b * 2], e1 = t2e[b * 2 + 1];
  int i0 = atomicAdd(&lcnt[e0], 1);
  int i1 = atomicAdd(&lcnt[e1], 1);
  __syncthreads();
  if (tid < NEXP) lbase[tid] = atomicAdd(&cursor[tid], lcnt[tid]);
  __syncthreads();
  int p0 = offs[e0] + lbase[e0] + i0;
  int p1 = offs[e1] + lbase[e1] + i1;
  tok[p0] = b;
  tok[p1] = b;
  rowpos[b * 2] = p0;
  rowpos[b * 2 + 1] = p1;
}

// src [R][C] f32 (expert z) -> dst [C][R] bf16; 64x64 tiles.
// LDS is float[64][65]: odd dword stride -> read bank = (r+c)%32, every bank hit
// exactly 2x across the wave (2-way = free, m136). Old u16[64][72] layout had
// bank = (4r+c/2)%32 with 4r == 4i mod 32 for r=8k+i -> 4 banks -> 16-way conflict.
__global__ __launch_bounds__(256) void transpose_cvt_kernel(
    const float* __restrict__ src, unsigned short* __restrict__ dst, int R, int C) {
  __shared__ float T[64][65];
  size_t eo = (size_t)blockIdx.z * (size_t)R * C;
  int c0 = blockIdx.x * 64, r0 = blockIdx.y * 64;
  int tid = threadIdx.x;
#pragma unroll
  for (int p = 0; p < 4; ++p) {
    int idx = p * 256 + tid;
    int r = idx >> 4, c4 = (idx & 15) * 4;
    float4 v = *(const float4*)(src + eo + (size_t)(r0 + r) * C + c0 + c4);
    T[r][c4] = v.x;
    T[r][c4 + 1] = v.y;
    T[r][c4 + 2] = v.z;
    T[r][c4 + 3] = v.w;
  }
  __syncthreads();
#pragma unroll
  for (int p = 0; p < 2; ++p) {
    int idx = p * 256 + tid;
    int c = idx >> 3, s8 = (idx & 7) * 8;
    u16x8 o;
#pragma unroll
    for (int i = 0; i < 8; ++i) o[i] = f2bf(T[s8 + i][c]);
    *(u16x8*)(dst + eo + (size_t)(c0 + c) * R + r0 + s8) = o;  // 16B aligned store
  }
}

// ---------------- grouped GEMM, 256x256 tile, BK=64, reg-double-buffered 4-phase pipeline ----------------
// Per phase: {issue ds_reads for phase p+1 into alternate reg set | issue 1 STAGE}
//            -> MFMA on regs loaded last phase -> counted vmcnt (P0/P2) -> lgkmcnt(0) -> barrier.
// Stage schedule per tile t: P0:B1(t+1)  P1:A0(t+2)  P2:B0(t+2)  P3:A1(t+2).
// Reads per tile t:          P0:B0(t)h1  P1:A1(t)+B1(t)h0  P2:B1(t)h1  P3:A0(t+1)+B0(t+1)h0.
// VM8 at end of P0 guarantees A1(t),B1(t) landed; VM8 at end of P2 guarantees A0(t+1),B0(t+1).
// Every physical region's stage comes >=2 barriers after its last read (WAR safe).
#define BAR() __builtin_amdgcn_s_barrier()
#define SB() __builtin_amdgcn_sched_barrier(0)
#define LG0() asm volatile("s_waitcnt lgkmcnt(0)" ::: "memory")
#define VMW(n) asm volatile("s_waitcnt vmcnt(" #n ")" ::: "memory")
#define RGN(t, mat, ks) (&LDS[(t) & 1][mat][ks][0][0])
#define STAGE(mat, P0p, P1p, t, ks)                                 \
  do {                                                              \
    unsigned short* _d = RGN(t, mat, ks) + wave * 512;              \
    gld16((P0p) + (size_t)(t) * 64 + (ks) * 32, _d);                \
    gld16((P1p) + (size_t)(t) * 64 + (ks) * 32, _d + 4096);         \
  } while (0)
#define RDA_TO(dst, t, ks)                                          \
  do {                                                              \
    const unsigned short* _p = RGN(t, 0, ks);                       \
    _Pragma("unroll") for (int n = 0; n < 4; ++n)                   \
        dst[n] = *(const bf16x8*)(_p + aoff[n]);                    \
  } while (0)
#define RDB_TO(dst, t, ks, h)                                       \
  do {                                                              \
    const unsigned short* _p = RGN(t, 1, ks);                       \
    _Pragma("unroll") for (int m = 0; m < 4; ++m)                   \
        dst[m] = *(const bf16x8*)(_p + boff2[h][m]);                \
  } while (0)
#define MMQ2(Av, Bv, h)                                             \
  do {                                                              \
    __builtin_amdgcn_s_setprio(1);                                  \
    _Pragma("unroll") for (int i = 0; i < 4; ++i)                   \
        _Pragma("unroll") for (int j = 0; j < 4; ++j)               \
            acc[i][(h)*4 + j] = __builtin_amdgcn_mfma_f32_16x16x32_bf16( \
                Av[i], Bv[j], acc[i][(h)*4 + j], 0, 0, 0);          \
    __builtin_amdgcn_s_setprio(0);                                  \
  } while (0)

template <int KD, bool GELU, bool GATHER>
__global__ __launch_bounds__(512, 2) void moe_gemm(
    const unsigned short* __restrict__ Bsrc, const unsigned short* __restrict__ Wt,
    const float* __restrict__ bias, const int* __restrict__ offs,
    const int* __restrict__ tileE, const int* __restrict__ tileM,
    const int* __restrict__ ntile, const int* __restrict__ tok,
    unsigned short* __restrict__ obuf, int ND) {
  constexpr int NT = KD / 64;
  static_assert(NT >= 3, "pipeline needs >=3 K-tiles");
  __shared__ __attribute__((aligned(16))) unsigned short LDS[2][2][2][256][32];  // 128 KiB
  int ty = blockIdx.y;
  if (ty >= *ntile) return;
  int e = tileE[ty], m0 = tileM[ty];
  int r0 = offs[e], rows = offs[e + 1] - r0;
  int n0 = blockIdx.x * 256;
  int tid = threadIdx.x, lane = tid & 63, wave = tid >> 6;
  int wn = wave & 3, wm = wave >> 2;
  int nbase = wn * 64, mbase = wm * 128;
  int fr = lane & 15, quad = lane >> 4;

  // staging source mapping: thread covers segs tid and 512+tid (linear LDS dest);
  // global seg pre-swizzled so that read-side XOR recovers it.
  int rs = tid >> 2;
  int ss = (tid & 3) ^ ((rs >> 1) & 3);  // same for both issues (row+128 keeps (r>>1)&3)
  const unsigned short* pA0 = Wt + ((size_t)e * ND + n0 + rs) * KD + ss * 8;
  const unsigned short* pA1 = pA0 + (size_t)128 * KD;
  int mr0 = min(m0 + rs, rows - 1), mr1 = min(m0 + 128 + rs, rows - 1);
  size_t br0, br1;
  if constexpr (GATHER) {
    br0 = (size_t)tok[r0 + mr0];
    br1 = (size_t)tok[r0 + mr1];
  } else {
    br0 = (size_t)(r0 + mr0);
    br1 = (size_t)(r0 + mr1);
  }
  const unsigned short* pB0 = Bsrc + br0 * KD + ss * 8;
  const unsigned short* pB1 = Bsrc + br1 * KD + ss * 8;

  // fragment read offsets (ushort units), swizzled
  int aoff[4], boff2[2][4];
#pragma unroll
  for (int n = 0; n < 4; ++n) {
    int rA = nbase + n * 16 + fr;
    aoff[n] = rA * 32 + (quad ^ ((rA >> 1) & 3)) * 8;
  }
#pragma unroll
  for (int h = 0; h < 2; ++h)
#pragma unroll
    for (int m = 0; m < 4; ++m) {
      int rB = mbase + h * 64 + m * 16 + fr;
      boff2[h][m] = rB * 32 + (quad ^ ((rB >> 1) & 3)) * 8;
    }

  f32x4 acc[4][8];
#pragma unroll
  for (int i = 0; i < 4; ++i)
#pragma unroll
    for (int j = 0; j < 8; ++j) acc[i][j] = (f32x4){0.f, 0.f, 0.f, 0.f};
  bf16x8 aE[4], aO[4], bE[4], bO[4];

  // prologue: tile0 complete + tile1 {A0,B0,A1}; B1(1) staged at (0,P0)
  STAGE(0, pA0, pA1, 0, 0);
  STAGE(1, pB0, pB1, 0, 0);
  STAGE(0, pA0, pA1, 0, 1);
  STAGE(1, pB0, pB1, 0, 1);
  STAGE(0, pA0, pA1, 1, 0);
  STAGE(1, pB0, pB1, 1, 0);
  STAGE(0, pA0, pA1, 1, 1);
  VMW(10);  // A0(0),B0(0) landed
  BAR();
  RDA_TO(aE, 0, 0);
  RDB_TO(bE, 0, 0, 0);
  LG0();
  SB();

  for (int t = 0; t < NT - 2; ++t) {
    // P0: compute (ks0,h0) | read B0(t)h1 | stage B1(t+1)
    RDB_TO(bO, t, 0, 1);
    STAGE(1, pB0, pB1, t + 1, 1);
    SB();
    MMQ2(aE, bE, 0);
    SB();
    VMW(8); LG0(); SB();
    BAR();
    // P1: compute (ks0,h1) | read A1(t), B1(t)h0 | stage A0(t+2)
    RDA_TO(aO, t, 1);
    RDB_TO(bE, t, 1, 0);
    STAGE(0, pA0, pA1, t + 2, 0);
    SB();
    MMQ2(aE, bO, 1);
    SB();
    LG0(); SB();
    BAR();
    // P2: compute (ks1,h0) | read B1(t)h1 | stage B0(t+2)
    RDB_TO(bO, t, 1, 1);
    STAGE(1, pB0, pB1, t + 2, 0);
    SB();
    MMQ2(aO, bE, 0);
    SB();
    VMW(8); LG0(); SB();
    BAR();
    // P3: compute (ks1,h1) | read A0(t+1), B0(t+1)h0 | stage A1(t+2)
    RDA_TO(aE, t + 1, 0);
    RDB_TO(bE, t + 1, 0, 0);
    STAGE(0, pA0, pA1, t + 2, 1);
    SB();
    MMQ2(aO, bO, 1);
    SB();
    LG0(); SB();
    BAR();
  }
  {  // tile NT-2: only B1(NT-1) left to stage
    int t = NT - 2;
    RDB_TO(bO, t, 0, 1);
    STAGE(1, pB0, pB1, t + 1, 1);
    SB(); MMQ2(aE, bE, 0); SB();
    VMW(8); LG0(); SB();
    BAR();
    RDA_TO(aO, t, 1);
    RDB_TO(bE, t, 1, 0);
    SB(); MMQ2(aE, bO, 1); SB();
    LG0(); SB();
    BAR();
    RDB_TO(bO, t, 1, 1);
    SB(); MMQ2(aO, bE, 0); SB();
    VMW(4); LG0(); SB();  // A0(NT-1),B0(NT-1) landed
    BAR();
    RDA_TO(aE, t + 1, 0);
    RDB_TO(bE, t + 1, 0, 0);
    SB(); MMQ2(aO, bO, 1); SB();
    LG0(); SB();
    BAR();
  }
  {  // tile NT-1: compute only
    int t = NT - 1;
    RDB_TO(bO, t, 0, 1);
    SB(); MMQ2(aE, bE, 0); SB();
    VMW(0); LG0(); SB();  // A1(NT-1),B1(NT-1) landed
    BAR();
    RDA_TO(aO, t, 1);
    RDB_TO(bE, t, 1, 0);
    SB(); MMQ2(aE, bO, 1); SB();
    LG0(); SB();
    BAR();
    RDB_TO(bO, t, 1, 1);
    SB(); MMQ2(aO, bE, 0); SB();
    LG0(); SB();
    BAR();
    SB(); MMQ2(aO, bO, 1); SB();
  }

  // epilogue: acc[i][J] -> out row m0+mbase+(J>>2)*64+(J&3)*16+fr,
  //           cols n0+nbase+i*16+quad*4+[0..3]
  const float* be = bias + (size_t)e * ND + n0 + nbase;
  float4 bv[4];
#pragma unroll
  for (int i = 0; i < 4; ++i) bv[i] = *(const float4*)(be + i * 16 + quad * 4);
#pragma unroll
  for (int j = 0; j < 8; ++j) {
    int grow = m0 + mbase + (j >> 2) * 64 + (j & 3) * 16 + fr;
    if (grow < rows) {
      unsigned short* yp = obuf + (size_t)(r0 + grow) * ND + n0 + nbase;
#pragma unroll
      for (int i = 0; i < 4; ++i) {
        float v0 = acc[i][j][0] + bv[i].x;
        float v1 = acc[i][j][1] + bv[i].y;
        float v2 = acc[i][j][2] + bv[i].z;
        float v3 = acc[i][j][3] + bv[i].w;
        if constexpr (GELU) {
          v0 = gelu_f(v0); v1 = gelu_f(v1); v2 = gelu_f(v2); v3 = gelu_f(v3);
        }
        ushort4 o;
        o.x = f2bf(v0); o.y = f2bf(v1); o.z = f2bf(v2); o.w = f2bf(v3);
        *(ushort4*)(yp + i * 16 + quad * 4) = o;
      }
    }
  }
}

// ---------------- combine: out[b] = w0*y[row0] + w1*y[row1] ----------------
__global__ __launch_bounds__(256) void combine_kernel(
    const unsigned short* __restrict__ ybuf, const int* __restrict__ rowpos,
    const float* __restrict__ t2w, float* __restrict__ out) {
  int idx = blockIdx.x * 256 + threadIdx.x;  // B*D/8 threads
  int b = idx >> 7;
  int c8 = (idx & 127) * 8;
  int p0 = rowpos[b * 2], p1 = rowpos[b * 2 + 1];
  float w0 = t2w[b * 2], w1 = t2w[b * 2 + 1];
  uint4 ya = *(const uint4*)(ybuf + (size_t)p0 * DDIM + c8);
  uint4 yb = *(const uint4*)(ybuf + (size_t)p1 * DDIM + c8);
  float4 o0, o1;
  o0.x = w0 * bflo(ya.x) + w1 * bflo(yb.x);
  o0.y = w0 * bfhi(ya.x) + w1 * bfhi(yb.x);
  o0.z = w0 * bflo(ya.y) + w1 * bflo(yb.y);
  o0.w = w0 * bfhi(ya.y) + w1 * bfhi(yb.y);
  o1.x = w0 * bflo(ya.z) + w1 * bflo(yb.z);
  o1.y = w0 * bfhi(ya.z) + w1 * bfhi(yb.z);
  o1.z = w0 * bflo(ya.w) + w1 * bflo(yb.w);
  o1.w = w0 * bfhi(ya.w) + w1 * bfhi(yb.w);
  float* op = out + (size_t)b * DDIM + c8;
  *(float4*)op = o0;
  *(float4*)(op + 4) = o1;
}

extern "C" void kernel_launch(void* const* d_in, const int* in_sizes, int n_in,
                              void* d_out, int out_size, void* d_ws, size_t ws_size,
                              hipStream_t stream) {
  const float* x = (const float*)d_in[0];
  const float* Wg = (const float*)d_in[1];
  const float* bg = (const float*)d_in[2];
  const float* W1 = (const float*)d_in[3];
  const float* b1 = (const float*)d_in[4];
  const float* W2 = (const float*)d_in[5];
  const float* b2 = (const float*)d_in[6];
  float* out = (float*)d_out;

  char* ws = (char*)d_ws;
  int* cnt = (int*)(ws + 0);
  int* cursor = (int*)(ws + 64);
  int* offs = (int*)(ws + 128);
  int* ntile = (int*)(ws + 192);
  int* tileE = (int*)(ws + 256);
  int* tileM = (int*)(ws + 896);
  int* t2e = (int*)(ws + 2048);
  float* t2w = (float*)(ws + 67584);
  int* tok = (int*)(ws + 133120);
  int* rowpos = (int*)(ws + 198656);
  char* big = ws + 264192;
  unsigned short* xb = (unsigned short*)big;                              // 16 MiB
  unsigned short* w1t = (unsigned short*)(big + 16777216);                // 64 MiB
  unsigned short* ybuf = w1t;  // alias: w1t dead after gemm1; ybuf needs 32 MiB
  unsigned short* w2t = (unsigned short*)(big + 16777216 + 67108864);     // 64 MiB
  unsigned short* hbuf = (unsigned short*)(big + 16777216 + 2 * 67108864);// 128 MiB

  (void)in_sizes; (void)n_in; (void)out_size; (void)ws_size;

  hipMemsetAsync(ws, 0, 256, stream);

  transpose_cvt_kernel<<<dim3(HDIM / 64, DDIM / 64, NEXP), 256, 0, stream>>>(W1, w1t, DDIM, HDIM);
  transpose_cvt_kernel<<<dim3(DDIM / 64, HDIM / 64, NEXP), 256, 0, stream>>>(W2, w2t, HDIM, DDIM);
  gating_kernel<<<B_TOK / 32, 256, 0, stream>>>(x, Wg, bg, t2e, t2w, cnt, xb);
  prefix_kernel<<<1, 1, 0, stream>>>(cnt, offs, tileE, tileM, ntile);
  scatter_kernel<<<B_TOK / 256, 256, 0, stream>>>(t2e, offs, cursor, tok, rowpos);
  moe_gemm<DDIM, true, true><<<dim3(HDIM / 256, MAXTILE), 512, 0, stream>>>(
      xb, w1t, b1, offs, tileE, tileM, ntile, tok, hbuf, HDIM);
  moe_gemm<HDIM, false, false><<<dim3(DDIM / 256, MAXTILE), 512, 0, stream>>>(
      hbuf, w2t, b2, offs, tileE, tileM, ntile, tok, ybuf, DDIM);
  combine_kernel<<<(B_TOK * DDIM) / (256 * 8), 256, 0, stream>>>(ybuf, rowpos, t2w, out);
}